// Round 13
// baseline (246.243 us; speedup 1.0000x reference)
//
#include <hip/hip_runtime.h>
#include <hip/hip_bf16.h>

#define TOKS 16384
#define HID  4096
#define NEXP 64
#define EPS  1e-4f   // flag threshold; trunc-split logit err ~6e-6 -> 16x margin

// ===== ws layout (floats) =====
// [0..63] prob sums | [64..127] argmax counts | int@[128] flag count |
// ints [192..192+16384) flag list | [16576) Bpack (1 MB) | [278720) P[16384][64] (4 MB)
#define WS_FLAGCNT  128
#define WS_FLAGLIST 192
#define WS_BPACK    16576
#define WS_PBASE    278720

typedef __attribute__((ext_vector_type(8))) short short8_t;
typedef __attribute__((ext_vector_type(4))) float f32x4;

static __device__ __forceinline__ unsigned short f2bf_rn(float x) {
    unsigned u = __builtin_bit_cast(unsigned, x);
    u = (u + 0x7fffu + ((u >> 16) & 1u)) >> 16;
    return (unsigned short)u;
}
static __device__ __forceinline__ float bf2f(unsigned short h) {
    return __builtin_bit_cast(float, (unsigned)h << 16);
}
static __device__ __forceinline__ void gl2lds16(const void* g, void* l) {
    __builtin_amdgcn_global_load_lds(
        (const __attribute__((address_space(1))) unsigned int*)g,
        (__attribute__((address_space(3))) unsigned int*)l, 16, 0, 0);
}

// ---------- prep: W -> frag-packed bf16, hi/lo planes split per (kt,nt) ----------
__global__ void moe_prep(const float* __restrict__ W, unsigned short* __restrict__ Bpk,
                         float* __restrict__ wsf) {
    const int idx = blockIdx.x * blockDim.x + threadIdx.x;
    if (idx < 192) wsf[idx] = 0.0f;
    if (idx >= NEXP * HID) return;
    const int n = idx >> 12;
    const int k = idx & 4095;
    const float w = W[idx];
    const unsigned short hi = f2bf_rn(w);
    const unsigned short lo = f2bf_rn(w - bf2f(hi));
    const int kt   = k >> 5;
    const int nt   = n >> 4;
    const int lane = (n & 15) | (((k >> 3) & 3) << 4);
    const int j    = k & 7;
    const int dst  = (((kt << 2) + nt) << 10) + (lane << 3) + j;
    Bpk[dst]       = hi;
    Bpk[dst + 512] = lo;
}

// ---------- kernel A: PURE pipelined MFMA GEMM -> P[tok][exp] (no epilogue) ----------
// Identical loop to R12: 256 blocks x 8 waves, 64 tok x 64 exp, 64 steps BK=64,
// 4-deep LDS, prefetch dist 2, counted vmcnt, one s_barrier/step. Ends with a
// coalesced logits store. ZERO cross-lane ops, ZERO atomics -> clean ablation probe.
__global__ __launch_bounds__(512, 1)
void moe_gemm(const float* __restrict__ X, const unsigned short* __restrict__ Bpk,
              float* __restrict__ P) {
    __shared__ __align__(16) float xbuf[4][64][64];
    __shared__ __align__(16) unsigned short bbuf[4][8192];
    float (*L)[68] = (float (*)[68])&xbuf[0][0][0];

    const int tid  = threadIdx.x;
    const int lane = tid & 63;
    const int w    = tid >> 6;
    const int mt   = w & 3;
    const int nh   = w >> 2;
    const int g    = lane >> 4;
    const int tok0 = blockIdx.x * 64;

    f32x4 acc[2];
    acc[0] = (f32x4){0.f, 0.f, 0.f, 0.f};
    acc[1] = (f32x4){0.f, 0.f, 0.f, 0.f};

    #define STAGE(bf, ss)                                                              \
    {                                                                                  \
        const int k0_ = (ss) << 6;                                                     \
        _Pragma("unroll")                                                              \
        for (int i = 0; i < 2; ++i) {                                                  \
            const int rg = (w << 3) + (i << 2) + g;                                    \
            const int ck = (lane & 15) ^ (rg & 15);                                    \
            gl2lds16(X + (size_t)(tok0 + rg) * HID + k0_ + (ck << 2),                  \
                     (void*)&xbuf[bf][(w << 3) + (i << 2)][0]);                        \
        }                                                                              \
        _Pragma("unroll")                                                              \
        for (int j = 0; j < 2; ++j) {                                                  \
            const int c1k = (w << 1) + j;                                              \
            gl2lds16((const char*)Bpk + ((size_t)(ss) << 14) + (c1k << 10) + (lane << 4), \
                     (void*)((char*)&bbuf[bf][0] + (c1k << 10)));                      \
        }                                                                              \
    }

    STAGE(0, 0);
    STAGE(1, 1);

    const int tr  = (mt << 4) + (lane & 15);
    const int rsw = lane & 15;

    for (int s = 0; s < 64; ++s) {
        const int cur = s & 3;
        {
            const int ss = (s + 2 < 64) ? (s + 2) : 63;
            STAGE((s + 2) & 3, ss);
        }
        asm volatile("s_waitcnt vmcnt(8)" ::: "memory");
        __builtin_amdgcn_s_barrier();
        __builtin_amdgcn_sched_barrier(0);

        const char* ab = (const char*)&xbuf[cur][tr][0];
        const char* bb = (const char*)&bbuf[cur][0];
        #pragma unroll
        for (int ktl = 0; ktl < 2; ++ktl) {
            const int cl = (ktl << 3) + (g << 1);
            const float4 a0 = *(const float4*)(ab + ((cl ^ rsw) << 4));
            const float4 a1 = *(const float4*)(ab + (((cl + 1) ^ rsw) << 4));
            const float xv[8] = {a0.x, a0.y, a0.z, a0.w, a1.x, a1.y, a1.z, a1.w};
            short8_t ah, al;
            #pragma unroll
            for (int j = 0; j < 8; ++j) {
                const unsigned u = __builtin_bit_cast(unsigned, xv[j]);
                ah[j] = (short)(u >> 16);
                const float hif = __builtin_bit_cast(float, u & 0xFFFF0000u);
                al[j] = (short)(__builtin_bit_cast(unsigned, xv[j] - hif) >> 16);
            }
            #pragma unroll
            for (int ntl = 0; ntl < 2; ++ntl) {
                const char* bp = bb + (((ktl << 2) + (nh << 1) + ntl) << 11) + (lane << 4);
                const short8_t bh = *(const short8_t*)bp;
                const short8_t bl = *(const short8_t*)(bp + 1024);
                acc[ntl] = __builtin_amdgcn_mfma_f32_16x16x32_bf16(ah, bh, acc[ntl], 0, 0, 0);
                acc[ntl] = __builtin_amdgcn_mfma_f32_16x16x32_bf16(al, bh, acc[ntl], 0, 0, 0);
                acc[ntl] = __builtin_amdgcn_mfma_f32_16x16x32_bf16(ah, bl, acc[ntl], 0, 0, 0);
            }
        }
    }
    asm volatile("s_waitcnt vmcnt(0)" ::: "memory");
    __syncthreads();

    // logits -> L (transpose via LDS), then fully-coalesced float4 store to P
    #pragma unroll
    for (int ntl = 0; ntl < 2; ++ntl)
        #pragma unroll
        for (int r = 0; r < 4; ++r)
            L[(mt << 4) + (g << 2) + r][(nh << 5) + (ntl << 4) + (lane & 15)] = acc[ntl][r];
    __syncthreads();
    {
        const int row = tid >> 3;              // 0..63
        const int c0  = (tid & 7) << 3;        // 0,8,..,56
        float* dst = P + (size_t)(tok0 + row) * NEXP + c0;
        const float* src = &L[row][c0];
        *(float4*)dst       = *(const float4*)src;
        *(float4*)(dst + 4) = *(const float4*)(src + 4);
    }
    #undef STAGE
}

// ---------- kernel B: standalone top-k (R3-proven) ----------
__global__ __launch_bounds__(256, 4)
void moe_topk(const float* __restrict__ P, float* __restrict__ out,
              float* __restrict__ wsf) {
    const int tid  = threadIdx.x;
    const int lane = tid & 63;
    const int wid  = tid >> 6;   // 0..3
    const int tok0 = blockIdx.x * 16;
    float* outIdx = out;
    float* outW   = out + TOKS * 8;
    int* flagcnt  = (int*)wsf + WS_FLAGCNT;
    int* flaglist = (int*)wsf + WS_FLAGLIST;

    float rp = 0.f;
    #pragma unroll
    for (int tt = 0; tt < 4; ++tt) {
        const int tok = tok0 + wid * 4 + tt;
        const float lg = P[(size_t)tok * NEXP + lane];

        // wave-wide softmax (lane = expert)
        float m = lg;
        #pragma unroll
        for (int o = 32; o; o >>= 1) m = fmaxf(m, __shfl_xor(m, o, 64));
        const float p = __expf(lg - m);
        float s = p;
        #pragma unroll
        for (int o = 32; o; o >>= 1) s += __shfl_xor(s, o, 64);
        const float inv_s = 1.0f / s;
        rp += p * inv_s;

        // top-9 (9th only for membership-gap check), ties -> lower index
        float v = lg;
        float lw[9]; int ik[9];
        #pragma unroll
        for (int k = 0; k < 9; ++k) {
            float bv = v; int bi = lane;
            #pragma unroll
            for (int o = 32; o; o >>= 1) {
                const float ov = __shfl_xor(bv, o, 64);
                const int   oi = __shfl_xor(bi, o, 64);
                if (ov > bv || (ov == bv && oi < bi)) { bv = ov; bi = oi; }
            }
            lw[k] = bv; ik[k] = bi;
            if (lane == bi) v = -3.0e38f;
        }
        float mingap = 3.0e38f;
        #pragma unroll
        for (int k = 0; k < 8; ++k) mingap = fminf(mingap, lw[k] - lw[k + 1]);

        float wk[8]; float denom = 1e-20f;
        #pragma unroll
        for (int k = 0; k < 8; ++k) { wk[k] = __expf(lw[k] - m) * inv_s; denom += wk[k]; }
        const float invd = 1.0f / denom;
        const size_t base = (size_t)tok * 8;
        if (lane < 8) {
            outIdx[base + lane] = (float)ik[lane];
            outW[base + lane]   = wk[lane] * invd;
        }
        if (lane == 0) {
            atomicAdd(&wsf[NEXP + ik[0]], 1.0f);
            if (mingap < EPS) {
                const int pos = atomicAdd(flagcnt, 1);
                if (pos < TOKS) flaglist[pos] = tok;
            }
        }
    }
    atomicAdd(&wsf[lane], rp);
}

// ---------- exact fp64 redo for flagged tokens ----------
__global__ __launch_bounds__(256, 2)
void moe_fix(const float* __restrict__ X, const float* __restrict__ W,
             float* __restrict__ out, float* __restrict__ wsf) {
    __shared__ double red[256];
    const int tid = threadIdx.x;
    const int e   = tid & 63;
    const int kc  = tid >> 6;
    const int nf  = min(*((int*)wsf + WS_FLAGCNT), TOKS);
    const int* flaglist = (const int*)wsf + WS_FLAGLIST;
    float* outIdx = out;
    float* outW   = out + TOKS * 8;

    for (int fi = blockIdx.x; fi < nf; fi += gridDim.x) {
        const int tok = flaglist[fi];
        const float* xrow = X + (size_t)tok * HID + kc * 1024;
        const float* wrow = W + (size_t)e  * HID + kc * 1024;
        double part = 0.0;
        for (int j = 0; j < 1024; j += 4) {
            const float4 xv = *(const float4*)(xrow + j);
            const float4 wv = *(const float4*)(wrow + j);
            part = fma((double)xv.x, (double)wv.x, part);
            part = fma((double)xv.y, (double)wv.y, part);
            part = fma((double)xv.z, (double)wv.z, part);
            part = fma((double)xv.w, (double)wv.w, part);
        }
        red[tid] = part;
        __syncthreads();
        if (tid < 64) {
            const double lg = ((red[tid] + red[64 + tid]) + red[128 + tid]) + red[192 + tid];
            const float lgf = (float)lg;
            float m = lgf;
            #pragma unroll
            for (int o = 32; o; o >>= 1) m = fmaxf(m, __shfl_xor(m, o, 64));
            const float p = __expf(lgf - m);
            float s = p;
            #pragma unroll
            for (int o = 32; o; o >>= 1) s += __shfl_xor(s, o, 64);
            const float inv_s = 1.0f / s;

            double v = lg;
            double bw[8]; int ik[8];
            #pragma unroll
            for (int k = 0; k < 8; ++k) {
                double bv = v; int bi = tid;
                #pragma unroll
                for (int o = 32; o; o >>= 1) {
                    const double ov = __shfl_xor(bv, o, 64);
                    const int    oi = __shfl_xor(bi, o, 64);
                    if (ov > bv || (ov == bv && oi < bi)) { bv = ov; bi = oi; }
                }
                bw[k] = bv; ik[k] = bi;
                if (tid == bi) v = -1.0e300;
            }
            float wk[8]; float denom = 1e-20f;
            #pragma unroll
            for (int k = 0; k < 8; ++k) {
                wk[k] = __expf((float)bw[k] - m) * inv_s; denom += wk[k];
            }
            const float invd = 1.0f / denom;
            const size_t base = (size_t)tok * 8;
            const int oldtop = (int)outIdx[base];
            if (tid < 8) {
                outIdx[base + tid] = (float)ik[tid];
                outW[base + tid]   = wk[tid] * invd;
            }
            if (tid == 0 && ik[0] != oldtop) {
                atomicAdd(&wsf[NEXP + oldtop], -1.0f);
                atomicAdd(&wsf[NEXP + ik[0]],  1.0f);
            }
        }
        __syncthreads();
    }
}

__global__ void moe_final(const float* __restrict__ wsf, float* __restrict__ out) {
    const int e = threadIdx.x;  // 64 threads
    float v = wsf[e] * wsf[NEXP + e];
    #pragma unroll
    for (int o = 32; o; o >>= 1) v += __shfl_xor(v, o, 64);
    if (e == 0)
        out[2 * TOKS * 8] = v * (64.0f / ((float)TOKS * (float)TOKS));
}

// ===== fallback monolith (proven R2 path) for small ws =====
__global__ void moe_init(float* __restrict__ wsf, int n) {
    const int i = blockIdx.x * blockDim.x + threadIdx.x;
    if (i < n) wsf[i] = 0.0f;
}

__global__ void moe_w_cvt(const float* __restrict__ W, double* __restrict__ Wd) {
    const int i = blockIdx.x * blockDim.x + threadIdx.x;
    if (i < NEXP * HID) Wd[i] = (double)W[i];
}

__global__ __launch_bounds__(512, 2)
void moe_mono(const float* __restrict__ X, const double* __restrict__ Wd,
              float* __restrict__ out, float* __restrict__ wsf) {
    __shared__ double xs[64][66];
    __shared__ double L2[64][65];
    const int tid  = threadIdx.x;
    const int lane = tid & 63;
    const int wid  = __builtin_amdgcn_readfirstlane(tid >> 6);
    const int tok0 = blockIdx.x * 64;
    double acc[8] = {0., 0., 0., 0., 0., 0., 0., 0.};
    for (int h0 = 0; h0 < HID; h0 += 64) {
        #pragma unroll
        for (int i = 0; i < 8; ++i) {
            const int li = tid + i * 512;
            xs[li >> 6][li & 63] = (double)X[((size_t)(tok0 + (li >> 6)) << 12) + (h0 + (li & 63))];
        }
        __syncthreads();
        const double* wchunk = Wd + (((size_t)(wid << 3)) << 12) + h0;
        #pragma unroll 2
        for (int hh = 0; hh < 64; hh += 2) {
            const double2 xv = *(const double2*)&xs[lane][hh];
            #pragma unroll
            for (int e = 0; e < 8; ++e) {
                const double* wr = wchunk + (((size_t)e) << 12) + hh;
                acc[e] = fma(xv.x, wr[0], acc[e]);
                acc[e] = fma(xv.y, wr[1], acc[e]);
            }
        }
        __syncthreads();
    }
    #pragma unroll
    for (int e = 0; e < 8; ++e) L2[lane][(wid << 3) + e] = acc[e];
    __syncthreads();
    float* outIdx = out;
    float* outW   = out + (TOKS * 8);
    float rp = 0.0f;
    for (int tt = 0; tt < 8; ++tt) {
        const int t = (wid << 3) + tt;
        const double lg = L2[t][lane];
        const float lgf = (float)lg;
        float m = lgf;
        #pragma unroll
        for (int o = 32; o; o >>= 1) m = fmaxf(m, __shfl_xor(m, o, 64));
        const float p = __expf(lgf - m);
        float s = p;
        #pragma unroll
        for (int o = 32; o; o >>= 1) s += __shfl_xor(s, o, 64);
        const float inv_s = 1.0f / s;
        rp += p * inv_s;
        double v = lg;
        float wk[8]; int ik[8];
        #pragma unroll
        for (int k = 0; k < 8; ++k) {
            double bv = v; int bi = lane;
            #pragma unroll
            for (int o = 32; o; o >>= 1) {
                const double ov = __shfl_xor(bv, o, 64);
                const int    oi = __shfl_xor(bi, o, 64);
                if (ov > bv || (ov == bv && oi < bi)) { bv = ov; bi = oi; }
            }
            wk[k] = __expf((float)bv - m) * inv_s; ik[k] = bi;
            if (lane == bi) v = -1.0e300;
        }
        if (lane == 0) {
            const float denom = (((wk[0]+wk[1])+(wk[2]+wk[3])) +
                                 ((wk[4]+wk[5])+(wk[6]+wk[7]))) + 1e-20f;
            const float invd = 1.0f / denom;
            const size_t base = ((size_t)(tok0 + t)) << 3;
            #pragma unroll
            for (int k = 0; k < 8; ++k) {
                outIdx[base + k] = (float)ik[k];
                outW[base + k]   = wk[k] * invd;
            }
            atomicAdd(&wsf[NEXP + ik[0]], 1.0f);
        }
    }
    atomicAdd(&wsf[lane], rp);
}

extern "C" void kernel_launch(void* const* d_in, const int* in_sizes, int n_in,
                              void* d_out, int out_size, void* d_ws, size_t ws_size,
                              hipStream_t stream) {
    const float* X = (const float*)d_in[0];   // [4,4096,4096] fp32
    const float* W = (const float*)d_in[1];   // [64,4096] fp32
    float* out = (float*)d_out;
    float* wsf = (float*)d_ws;

    const size_t need = 4ull * (WS_PBASE + (size_t)TOKS * NEXP);  // ~5.3 MB

    if (ws_size >= need) {
        unsigned short* Bpk = (unsigned short*)(wsf + WS_BPACK);
        float* P = wsf + WS_PBASE;
        moe_prep<<<(NEXP * HID + 255) / 256, 256, 0, stream>>>(W, Bpk, wsf);
        moe_gemm<<<TOKS / 64, 512, 0, stream>>>(X, Bpk, P);
        moe_topk<<<TOKS / 16, 256, 0, stream>>>(P, out, wsf);
        moe_fix<<<256, 256, 0, stream>>>(X, W, out, wsf);
        moe_final<<<1, 64, 0, stream>>>(wsf, out);
    } else {
        double* Wd = (double*)d_ws;
        float* wsf2 = (float*)(Wd + NEXP * HID);
        moe_w_cvt<<<(NEXP * HID + 255) / 256, 256, 0, stream>>>(W, Wd);
        moe_init<<<1, 256, 0, stream>>>(wsf2, 128);
        moe_mono<<<TOKS / 64, 512, 0, stream>>>(X, Wd, out, wsf2);
        moe_final<<<1, 64, 0, stream>>>(wsf2, out);
    }
}

// Round 14
// 210.578 us; speedup vs baseline: 1.1694x; 1.1694x over previous
//
#include <hip/hip_runtime.h>
#include <hip/hip_bf16.h>

#define TOKS 16384
#define HID  4096
#define NEXP 64
#define EPS  1e-4f   // flag threshold; trunc-split logit err ~6e-6 -> 16x margin

// ===== ws layout (floats) =====
// [0..63] prob sums | [64..127] argmax counts | int@[128] flag count |
// ints [192..192+16384) flag list | [16576) Bpack (1 MB, bf16 hi/lo plane-split frag-pack)
#define WS_FLAGCNT  128
#define WS_FLAGLIST 192
#define WS_BPACK    16576

typedef __attribute__((ext_vector_type(8))) short short8_t;
typedef __attribute__((ext_vector_type(4))) float f32x4;

static __device__ __forceinline__ unsigned short f2bf_rn(float x) {
    unsigned u = __builtin_bit_cast(unsigned, x);
    u = (u + 0x7fffu + ((u >> 16) & 1u)) >> 16;
    return (unsigned short)u;
}
static __device__ __forceinline__ float bf2f(unsigned short h) {
    return __builtin_bit_cast(float, (unsigned)h << 16);
}
static __device__ __forceinline__ void gl2lds16(const void* g, void* l) {
    __builtin_amdgcn_global_load_lds(
        (const __attribute__((address_space(1))) unsigned int*)g,
        (__attribute__((address_space(3))) unsigned int*)l, 16, 0, 0);
}

// ---------- prep: W -> frag-packed bf16, hi/lo planes split per (kt,nt) ----------
// u16 index: (kt*4+nt)*1024 + plane*512 + lane*8 + j ; lane=(n&15)|(((k>>3)&3)<<4), j=k&7
__global__ void moe_prep(const float* __restrict__ W, unsigned short* __restrict__ Bpk,
                         float* __restrict__ wsf) {
    const int idx = blockIdx.x * blockDim.x + threadIdx.x;
    if (idx < 192) wsf[idx] = 0.0f;
    if (idx >= NEXP * HID) return;
    const int n = idx >> 12;
    const int k = idx & 4095;
    const float w = W[idx];
    const unsigned short hi = f2bf_rn(w);
    const unsigned short lo = f2bf_rn(w - bf2f(hi));
    const int kt   = k >> 5;
    const int nt   = n >> 4;
    const int lane = (n & 15) | (((k >> 3) & 3) << 4);
    const int j    = k & 7;
    const int dst  = (((kt << 2) + nt) << 10) + (lane << 3) + j;
    Bpk[dst]       = hi;
    Bpk[dst + 512] = lo;
}

// ---------- fused: LINEAR-staged pipelined MFMA GEMM + softmax + bitonic top-8 ----------
// 256 blocks x 512 thr (8 waves). 64 tok x 64 exp per block, 64 K-steps of 64.
// X staged into PADDED rows [64][68] via lane-MONOTONIC gl_lds (1 KB linear chunks;
// 272 B = 17x16 B rows, pad lanes land in pad bytes). A-frag ds_read_b128 is then
// 2-way-bank (free). All staging instructions are lane-monotonic -> TA coalesces.
// 4-deep buffers, prefetch distance 2, counted vmcnt(10), one s_barrier per step.
__global__ __launch_bounds__(512, 1)
void moe_fused(const float* __restrict__ X, const unsigned short* __restrict__ Bpk,
               float* __restrict__ out, float* __restrict__ wsf) {
    __shared__ __align__(16) float xbuf[4][64][68];           // 69632 B
    __shared__ __align__(16) unsigned short bbuf[4][8192];    // 65536 B
    float (*L)[68] = (float (*)[68])&xbuf[0][0][0];           // epilogue alias

    const int tid  = threadIdx.x;
    const int lane = tid & 63;
    const int w    = tid >> 6;                 // 0..7
    const int mt   = w & 3;                    // m-tile (16 tokens)
    const int nh   = w >> 2;                   // n-half
    const int g    = lane >> 4;                // 0..3
    const int tok0 = blockIdx.x * 64;

    f32x4 acc[2];
    acc[0] = (f32x4){0.f, 0.f, 0.f, 0.f};
    acc[1] = (f32x4){0.f, 0.f, 0.f, 0.f};

    // X staging map: slot t = w*3+i covers padded bytes [t17*1024, +1024) of xbuf[.]
    // lane L -> byte off = t17*1024 + 16L; row = off/272 (17 x 16B per row), rb = off%272.
    // rb >= 256 is pad -> harmless src. Lane order within each row is MONOTONIC.
    int ldsoff[3]; size_t gxb[3];
    #pragma unroll
    for (int i = 0; i < 3; ++i) {
        int t = w * 3 + i; if (t >= 17) t -= 17;          // dup slots write same data
        const int off = t * 1024 + (lane << 4);
        const int row = off / 272;
        const int rb  = off - row * 272;
        const int col = (rb < 256) ? (rb >> 2) : 0;       // floats
        ldsoff[i] = t * 1024;
        gxb[i] = (size_t)(tok0 + row) * HID + col;
    }

    #define STAGE(bf, ss)                                                              \
    {                                                                                  \
        const int k0_ = (ss) << 6;                                                     \
        _Pragma("unroll")                                                              \
        for (int i = 0; i < 3; ++i)                                                    \
            gl2lds16(X + gxb[i] + k0_, (void*)((char*)&xbuf[bf][0][0] + ldsoff[i]));   \
        _Pragma("unroll")                                                              \
        for (int j = 0; j < 2; ++j) {                                                  \
            const int c1k = (w << 1) + j;                                              \
            gl2lds16((const char*)Bpk + ((size_t)(ss) << 14) + (c1k << 10) + (lane << 4), \
                     (void*)((char*)&bbuf[bf][0] + (c1k << 10)));                      \
        }                                                                              \
    }

    STAGE(0, 0);
    STAGE(1, 1);

    const int tr = (mt << 4) + (lane & 15);    // token row for A frags

    for (int s = 0; s < 64; ++s) {
        const int cur = s & 3;
        {
            const int ss = (s + 2 < 64) ? (s + 2) : 63;   // tail dups harmless
            STAGE((s + 2) & 3, ss);
        }
        // wait for stage(s) only (5 instrs/wave/stage): leave s+1, s+2 (10) in flight
        asm volatile("s_waitcnt vmcnt(10)" ::: "memory");
        __builtin_amdgcn_s_barrier();
        __builtin_amdgcn_sched_barrier(0);

        const char* ab = (const char*)&xbuf[cur][0][0] + tr * 272;
        const char* bb = (const char*)&bbuf[cur][0];
        #pragma unroll
        for (int ktl = 0; ktl < 2; ++ktl) {
            const int cl = (ktl << 3) + (g << 1);
            const float4 a0 = *(const float4*)(ab + (cl << 4));
            const float4 a1 = *(const float4*)(ab + (cl << 4) + 16);
            const float xv[8] = {a0.x, a0.y, a0.z, a0.w, a1.x, a1.y, a1.z, a1.w};
            short8_t ah, al;
            #pragma unroll
            for (int j = 0; j < 8; ++j) {      // exact truncation split: x = hif + lof
                const unsigned u = __builtin_bit_cast(unsigned, xv[j]);
                ah[j] = (short)(u >> 16);
                const float hif = __builtin_bit_cast(float, u & 0xFFFF0000u);
                al[j] = (short)(__builtin_bit_cast(unsigned, xv[j] - hif) >> 16);
            }
            #pragma unroll
            for (int ntl = 0; ntl < 2; ++ntl) {
                const char* bp = bb + (((ktl << 2) + (nh << 1) + ntl) << 11) + (lane << 4);
                const short8_t bh = *(const short8_t*)bp;
                const short8_t bl = *(const short8_t*)(bp + 1024);
                acc[ntl] = __builtin_amdgcn_mfma_f32_16x16x32_bf16(ah, bh, acc[ntl], 0, 0, 0);
                acc[ntl] = __builtin_amdgcn_mfma_f32_16x16x32_bf16(al, bh, acc[ntl], 0, 0, 0);
                acc[ntl] = __builtin_amdgcn_mfma_f32_16x16x32_bf16(ah, bl, acc[ntl], 0, 0, 0);
            }
        }
        // writer targets (s+3)&3 next iter; lag-1 readers hold (s)&3 -> no collision
    }
    asm volatile("s_waitcnt vmcnt(0)" ::: "memory");
    __syncthreads();

    // ---- logits -> L[token][expert] (aliases dead staging bufs, same 68 stride) ----
    #pragma unroll
    for (int ntl = 0; ntl < 2; ++ntl)
        #pragma unroll
        for (int r = 0; r < 4; ++r)
            L[(mt << 4) + (g << 2) + r][(nh << 5) + (ntl << 4) + (lane & 15)] = acc[ntl][r];
    __syncthreads();

    // ---- epilogue: wave w handles tokens w*8 .. w*8+7; lane = expert ----
    float* outIdx = out;
    float* outW   = out + TOKS * 8;
    int* flagcnt  = (int*)wsf + WS_FLAGCNT;
    int* flaglist = (int*)wsf + WS_FLAGLIST;

    float rp = 0.f;
    #pragma unroll
    for (int tt = 0; tt < 8; ++tt) {
        const int tl = (w << 3) + tt;
        const float lg = L[tl][lane];

        // bitonic sort-64, descending by (value, then lower index first)
        float v = lg; int idx = lane;
        #pragma unroll
        for (int size = 2; size <= 64; size <<= 1) {
            #pragma unroll
            for (int str = size >> 1; str > 0; str >>= 1) {
                const float ov = __shfl_xor(v, str, 64);
                const int   oi = __shfl_xor(idx, str, 64);
                const bool pb = (ov > v) || (ov == v && oi < idx);
                const bool keepFirst = ((lane & str) == 0) == ((lane & size) == 0);
                if (pb == keepFirst) { v = ov; idx = oi; }
            }
        }

        const float m = __shfl(v, 0, 64);
        const float p = __expf(lg - m);
        float sdenom = p;
        #pragma unroll
        for (int o = 32; o; o >>= 1) sdenom += __shfl_xor(sdenom, o, 64);
        const float inv_s = 1.0f / sdenom;
        rp += p * inv_s;

        const float wkv = __expf(v - m) * inv_s;
        float d8 = (lane < 8) ? wkv : 0.f;
        #pragma unroll
        for (int o = 1; o < 8; o <<= 1) d8 += __shfl_xor(d8, o, 64);
        const float invd = 1.0f / (d8 + 1e-20f);
        const float nv = __shfl_down(v, 1, 64);
        const bool flg = __any(lane < 8 && (v - nv) < EPS);

        const int gtok = tok0 + tl;
        if (lane < 8) {
            outIdx[(size_t)gtok * 8 + lane] = (float)idx;
            outW[(size_t)gtok * 8 + lane]   = wkv * invd;
        }
        if (lane == 0) {
            atomicAdd(&wsf[NEXP + idx], 1.0f);
            if (flg) {
                const int pos = atomicAdd(flagcnt, 1);
                if (pos < TOKS) flaglist[pos] = gtok;
            }
        }
    }
    atomicAdd(&wsf[lane], rp);
    #undef STAGE
}

// ---------- exact fp64 redo for flagged tokens ----------
__global__ __launch_bounds__(256, 2)
void moe_fix(const float* __restrict__ X, const float* __restrict__ W,
             float* __restrict__ out, float* __restrict__ wsf) {
    __shared__ double red[256];
    const int tid = threadIdx.x;
    const int e   = tid & 63;
    const int kc  = tid >> 6;
    const int nf  = min(*((int*)wsf + WS_FLAGCNT), TOKS);
    const int* flaglist = (const int*)wsf + WS_FLAGLIST;
    float* outIdx = out;
    float* outW   = out + TOKS * 8;

    for (int fi = blockIdx.x; fi < nf; fi += gridDim.x) {
        const int tok = flaglist[fi];
        const float* xrow = X + (size_t)tok * HID + kc * 1024;
        const float* wrow = W + (size_t)e  * HID + kc * 1024;
        double part = 0.0;
        for (int j = 0; j < 1024; j += 4) {
            const float4 xv = *(const float4*)(xrow + j);
            const float4 wv = *(const float4*)(wrow + j);
            part = fma((double)xv.x, (double)wv.x, part);
            part = fma((double)xv.y, (double)wv.y, part);
            part = fma((double)xv.z, (double)wv.z, part);
            part = fma((double)xv.w, (double)wv.w, part);
        }
        red[tid] = part;
        __syncthreads();
        if (tid < 64) {
            const double lg = ((red[tid] + red[64 + tid]) + red[128 + tid]) + red[192 + tid];
            const float lgf = (float)lg;
            float m = lgf;
            #pragma unroll
            for (int o = 32; o; o >>= 1) m = fmaxf(m, __shfl_xor(m, o, 64));
            const float p = __expf(lgf - m);
            float s = p;
            #pragma unroll
            for (int o = 32; o; o >>= 1) s += __shfl_xor(s, o, 64);
            const float inv_s = 1.0f / s;

            double v = lg;
            double bw[8]; int ik[8];
            #pragma unroll
            for (int k = 0; k < 8; ++k) {
                double bv = v; int bi = tid;
                #pragma unroll
                for (int o = 32; o; o >>= 1) {
                    const double ov = __shfl_xor(bv, o, 64);
                    const int    oi = __shfl_xor(bi, o, 64);
                    if (ov > bv || (ov == bv && oi < bi)) { bv = ov; bi = oi; }
                }
                bw[k] = bv; ik[k] = bi;
                if (tid == bi) v = -1.0e300;
            }
            float wk[8]; float denom = 1e-20f;
            #pragma unroll
            for (int k = 0; k < 8; ++k) {
                wk[k] = __expf((float)bw[k] - m) * inv_s; denom += wk[k];
            }
            const float invd = 1.0f / denom;
            const size_t base = (size_t)tok * 8;
            const int oldtop = (int)outIdx[base];
            if (tid < 8) {
                outIdx[base + tid] = (float)ik[tid];
                outW[base + tid]   = wk[tid] * invd;
            }
            if (tid == 0 && ik[0] != oldtop) {
                atomicAdd(&wsf[NEXP + oldtop], -1.0f);
                atomicAdd(&wsf[NEXP + ik[0]],  1.0f);
            }
        }
        __syncthreads();
    }
}

__global__ void moe_final(const float* __restrict__ wsf, float* __restrict__ out) {
    const int e = threadIdx.x;  // 64 threads
    float v = wsf[e] * wsf[NEXP + e];
    #pragma unroll
    for (int o = 32; o; o >>= 1) v += __shfl_xor(v, o, 64);
    if (e == 0)
        out[2 * TOKS * 8] = v * (64.0f / ((float)TOKS * (float)TOKS));
}

// ===== fallback monolith (proven R2 path) for small ws =====
__global__ void moe_init(float* __restrict__ wsf, int n) {
    const int i = blockIdx.x * blockDim.x + threadIdx.x;
    if (i < n) wsf[i] = 0.0f;
}

__global__ void moe_w_cvt(const float* __restrict__ W, double* __restrict__ Wd) {
    const int i = blockIdx.x * blockDim.x + threadIdx.x;
    if (i < NEXP * HID) Wd[i] = (double)W[i];
}

__global__ __launch_bounds__(512, 2)
void moe_mono(const float* __restrict__ X, const double* __restrict__ Wd,
              float* __restrict__ out, float* __restrict__ wsf) {
    __shared__ double xs[64][66];
    __shared__ double L2[64][65];
    const int tid  = threadIdx.x;
    const int lane = tid & 63;
    const int wid  = __builtin_amdgcn_readfirstlane(tid >> 6);
    const int tok0 = blockIdx.x * 64;
    double acc[8] = {0., 0., 0., 0., 0., 0., 0., 0.};
    for (int h0 = 0; h0 < HID; h0 += 64) {
        #pragma unroll
        for (int i = 0; i < 8; ++i) {
            const int li = tid + i * 512;
            xs[li >> 6][li & 63] = (double)X[((size_t)(tok0 + (li >> 6)) << 12) + (h0 + (li & 63))];
        }
        __syncthreads();
        const double* wchunk = Wd + (((size_t)(wid << 3)) << 12) + h0;
        #pragma unroll 2
        for (int hh = 0; hh < 64; hh += 2) {
            const double2 xv = *(const double2*)&xs[lane][hh];
            #pragma unroll
            for (int e = 0; e < 8; ++e) {
                const double* wr = wchunk + (((size_t)e) << 12) + hh;
                acc[e] = fma(xv.x, wr[0], acc[e]);
                acc[e] = fma(xv.y, wr[1], acc[e]);
            }
        }
        __syncthreads();
    }
    #pragma unroll
    for (int e = 0; e < 8; ++e) L2[lane][(wid << 3) + e] = acc[e];
    __syncthreads();
    float* outIdx = out;
    float* outW   = out + (TOKS * 8);
    float rp = 0.0f;
    for (int tt = 0; tt < 8; ++tt) {
        const int t = (wid << 3) + tt;
        const double lg = L2[t][lane];
        const float lgf = (float)lg;
        float m = lgf;
        #pragma unroll
        for (int o = 32; o; o >>= 1) m = fmaxf(m, __shfl_xor(m, o, 64));
        const float p = __expf(lgf - m);
        float s = p;
        #pragma unroll
        for (int o = 32; o; o >>= 1) s += __shfl_xor(s, o, 64);
        const float inv_s = 1.0f / s;
        rp += p * inv_s;
        double v = lg;
        float wk[8]; int ik[8];
        #pragma unroll
        for (int k = 0; k < 8; ++k) {
            double bv = v; int bi = lane;
            #pragma unroll
            for (int o = 32; o; o >>= 1) {
                const double ov = __shfl_xor(bv, o, 64);
                const int    oi = __shfl_xor(bi, o, 64);
                if (ov > bv || (ov == bv && oi < bi)) { bv = ov; bi = oi; }
            }
            wk[k] = __expf((float)bv - m) * inv_s; ik[k] = bi;
            if (lane == bi) v = -1.0e300;
        }
        if (lane == 0) {
            const float denom = (((wk[0]+wk[1])+(wk[2]+wk[3])) +
                                 ((wk[4]+wk[5])+(wk[6]+wk[7]))) + 1e-20f;
            const float invd = 1.0f / denom;
            const size_t base = ((size_t)(tok0 + t)) << 3;
            #pragma unroll
            for (int k = 0; k < 8; ++k) {
                outIdx[base + k] = (float)ik[k];
                outW[base + k]   = wk[k] * invd;
            }
            atomicAdd(&wsf[NEXP + ik[0]], 1.0f);
        }
    }
    atomicAdd(&wsf[lane], rp);
}

extern "C" void kernel_launch(void* const* d_in, const int* in_sizes, int n_in,
                              void* d_out, int out_size, void* d_ws, size_t ws_size,
                              hipStream_t stream) {
    const float* X = (const float*)d_in[0];   // [4,4096,4096] fp32
    const float* W = (const float*)d_in[1];   // [64,4096] fp32
    float* out = (float*)d_out;
    float* wsf = (float*)d_ws;

    const size_t need = 4ull * WS_BPACK + 2ull * 524288;  // slots + Bpack ~ 1.1 MB

    if (ws_size >= need) {
        unsigned short* Bpk = (unsigned short*)(wsf + WS_BPACK);
        moe_prep<<<(NEXP * HID + 255) / 256, 256, 0, stream>>>(W, Bpk, wsf);
        moe_fused<<<TOKS / 64, 512, 0, stream>>>(X, Bpk, out, wsf);
        moe_fix<<<256, 256, 0, stream>>>(X, W, out, wsf);
        moe_final<<<1, 64, 0, stream>>>(wsf, out);
    } else {
        double* Wd = (double*)d_ws;
        float* wsf2 = (float*)(Wd + NEXP * HID);
        moe_w_cvt<<<(NEXP * HID + 255) / 256, 256, 0, stream>>>(W, Wd);
        moe_init<<<1, 256, 0, stream>>>(wsf2, 128);
        moe_mono<<<TOKS / 64, 512, 0, stream>>>(X, Wd, out, wsf2);
        moe_final<<<1, 64, 0, stream>>>(wsf2, out);
    }
}